// Round 11
// baseline (602.444 us; speedup 1.0000x reference)
//
#include <hip/hip_runtime.h>
#include <hip/hip_bf16.h>
#include <cstdint>

typedef unsigned long long u64;
typedef unsigned int u32;
typedef unsigned short u16;

constexpr int NB   = 8;     // batch
constexpr int NL   = 4096;  // H*W
constexpr int ND   = 192;   // D_INNER
constexpr int NDM  = 96;    // D_MODEL
constexpr int NE   = 8064;  // edges per batch
constexpr int NEH  = 4032;  // horizontal edges
constexpr int SENT = 8190;  // Euler sentinel (m = 2*4095)

__device__ __forceinline__ float siluf(float x){ return x / (1.f + expf(-x)); }
__device__ __forceinline__ float softplusf(float x){ return fmaxf(x,0.f) + log1pf(expf(-fabsf(x))); }

__device__ __forceinline__ float wred_f(float v){
  #pragma unroll
  for (int o=32;o;o>>=1) v += __shfl_down(v,o);
  return __shfl(v,0);
}
__device__ __forceinline__ double wred_d(double v){
  #pragma unroll
  for (int o=32;o;o>>=1) v += __shfl_down(v,o);
  return __shfl(v,0);
}

// edge e -> endpoints (reference ordering: horizontal first, row-major, then vertical); u < v always
__device__ __forceinline__ void edge_uv(int e, int& u, int& v){
  if (e < NEH){ int r=e/63; int c=e-r*63; u=(r<<6)+c; v=u+1; }
  else        { u=e-NEH; v=u+64; }
}

// ---------------- K1: xz = x @ in_proj_w.T (f32, LDS-tiled); split -> xc_pre, z=silu ----------------
__global__ __launch_bounds__(256) void k1_inproj(const float* __restrict__ x, const float* __restrict__ w,
                                                 float* __restrict__ xc_pre, float* __restrict__ zb){
  __shared__ float sx[96*33];       // [k][row0..31], pad 33
  __shared__ float sw[96*97];       // [k][col0..95], pad 97
  const int tid = threadIdx.x;
  const int brow = blockIdx.x >> 2;
  const int cc   = blockIdx.x & 3;
  const int row0 = brow * 32;
  {
    const float* src = x + (size_t)row0*96;
    for (int i=tid; i<32*96; i+=256){
      int r = i/96, k = i - r*96;
      sx[k*33 + r] = src[i];
    }
  }
  {
    const float* src = w + (size_t)cc*96*96;
    for (int i=tid; i<96*96; i+=256){
      int c = i/96, k = i - c*96;
      sw[k*97 + c] = src[i];
    }
  }
  __syncthreads();
  const int rq = tid >> 5;
  const int cq = tid & 31;
  float acc[4][3];
  #pragma unroll
  for (int a=0;a<4;++a)
    #pragma unroll
    for (int bcl=0;bcl<3;++bcl) acc[a][bcl] = 0.f;
  #pragma unroll 4
  for (int k=0;k<96;++k){
    float4 xa = *(const float4*)&sx[k*33 + rq*4];
    float w0 = sw[k*97 + cq*3 + 0];
    float w1 = sw[k*97 + cq*3 + 1];
    float w2 = sw[k*97 + cq*3 + 2];
    acc[0][0] += xa.x*w0; acc[0][1] += xa.x*w1; acc[0][2] += xa.x*w2;
    acc[1][0] += xa.y*w0; acc[1][1] += xa.y*w1; acc[1][2] += xa.y*w2;
    acc[2][0] += xa.z*w0; acc[2][1] += xa.z*w1; acc[2][2] += xa.z*w2;
    acc[3][0] += xa.w*w0; acc[3][1] += xa.w*w1; acc[3][2] += xa.w*w2;
  }
  #pragma unroll
  for (int a=0;a<4;++a){
    size_t row = row0 + rq*4 + a;
    #pragma unroll
    for (int bcl=0;bcl<3;++bcl){
      int c = cq*3 + bcl;
      float v = acc[a][bcl];
      if (cc < 2) xc_pre[row*ND + cc*96 + c] = v;
      else        zb[row*ND + (cc-2)*96 + c] = siluf(v);
    }
  }
}

// ---------------- K2: depthwise 3x3 conv (SAME) + bias + silu (f32) -> xs ----------------
__global__ __launch_bounds__(256) void k2_conv(const float* __restrict__ xc_pre, const float* __restrict__ cw,
                                               const float* __restrict__ cb, float* __restrict__ xs){
  int idx = blockIdx.x*256 + threadIdx.x;
  if (idx >= NB*NL*ND) return;
  int d = idx % ND;
  int l = (idx/ND) & 4095;
  int b = idx / (ND*NL);
  int r = l >> 6, c = l & 63;
  float acc = cb[d];
  #pragma unroll
  for (int dy=-1; dy<=1; ++dy){
    int rr = r+dy; if (rr<0 || rr>63) continue;
    #pragma unroll
    for (int dx=-1; dx<=1; ++dx){
      int cc = c+dx; if (cc<0 || cc>63) continue;
      acc += xc_pre[((size_t)b*NL + (rr<<6) + cc)*ND + d] * cw[d*9 + (dy+1)*3 + (dx+1)];
    }
  }
  xs[idx] = siluf(acc);
}

// ---------------- K3: x_dbl dots, dts->softplus, ew/BX channel-major via LDS write-batching ----------------
__global__ __launch_bounds__(1024) void k3_ssm(const float* __restrict__ xs, const float* __restrict__ xpw,
                                               const float* __restrict__ dtw, const float* __restrict__ dtb,
                                               const float* __restrict__ alog,
                                               float* __restrict__ ew_cm, float* __restrict__ up_cm,
                                               float* __restrict__ Cs, double* __restrict__ norms){
  __shared__ float s_ew[192*17];    // [d][l0..15], pad 17 -> conflict-free
  __shared__ float s_up[192*17];
  const int wid  = threadIdx.x >> 6;            // 0..15: which l within the tile
  const int lane = threadIdx.x & 63;
  const int gid  = blockIdx.x*16 + wid;         // b*NL + l  (4096%16==0: no batch straddle)
  const int b    = gid >> 12;
  const float* xr = xs + (size_t)gid*ND;
  float xv[3];
  #pragma unroll
  for (int j=0;j<3;++j) xv[j] = xr[lane + 64*j];
  float sums[8];
  #pragma unroll
  for (int cc=0; cc<8; ++cc){
    float p = 0.f;
    #pragma unroll
    for (int j=0;j<3;++j) p += xv[j]*xpw[cc*ND + lane + 64*j];
    sums[cc] = wred_f(p);
  }
  double n2 = 0.0;
  #pragma unroll
  for (int j=0;j<3;++j) n2 += (double)xv[j]*(double)xv[j];
  n2 = wred_d(n2);
  if (lane==0){
    Cs[gid] = sums[7];
    norms[gid] = fmax(sqrt(n2), 1e-8);
  }
  float Bv = sums[6];
  #pragma unroll
  for (int j=0;j<3;++j){
    int d = lane + 64*j;
    float dtv = dtb[d];
    #pragma unroll
    for (int r=0;r<6;++r) dtv += sums[r]*dtw[d*6+r];
    float sp = softplusf(dtv);
    float A  = -expf(alog[d]);
    s_ew[d*17 + wid] = expf(sp*A);
    s_up[d*17 + wid] = sp*Bv*xv[j];   // BX = dts*Bs*xs
  }
  __syncthreads();
  // cooperative channel-major write: thread t -> (dd = t>>4, lq = t&15); full 64B line per dd
  const int dq = threadIdx.x >> 4;              // 0..63
  const int lq = threadIdx.x & 15;
  const int lb = (blockIdx.x*16) & 4095;        // l tile base within batch
  #pragma unroll
  for (int q=0;q<3;++q){
    int dd = dq + 64*q;
    size_t o = ((size_t)(b*ND + dd))*NL + lb + lq;
    ew_cm[o] = s_ew[dd*17 + lq];
    up_cm[o] = s_up[dd*17 + lq];
  }
}

// ---------------- K4: per-edge f64 normalized dot -> sortable u64 key ----------------
__global__ __launch_bounds__(256) void k4_keys(const float* __restrict__ xs, const double* __restrict__ norms,
                                               u64* __restrict__ keys){
  int gid = blockIdx.x*4 + (threadIdx.x>>6);   // one wave per (b,e)
  if (gid >= NB*NE) return;
  int lane = threadIdx.x & 63;
  int b = gid / NE, e = gid - b*NE;
  int u, v; edge_uv(e, u, v);
  const float* xu = xs + ((size_t)(b*NL + u))*ND;
  const float* xw = xs + ((size_t)(b*NL + v))*ND;
  double nu = norms[b*NL+u], nv = norms[b*NL+v];
  double dot = 0.0;
  #pragma unroll
  for (int j=0;j<3;++j){
    int d = lane + 64*j;
    double du = (double)xu[d] / nu;     // fn = f/norm per element, like reference
    double dv = (double)xw[d] / nv;
    dot += du*dv;
  }
  dot = wred_d(dot);
  if (lane==0){
    long long q = __double2ll_rn((1.0 - dot) * 17592186044416.0);  // 2^44
    if (q < 0) q = 0;
    keys[gid] = (((u64)q) << 13) | (u64)e;
  }
}

// ---------------- K5: Boruvka MST + Euler-tour depth/parent (single Wyllie + positional scan) ----------------
// Hierarchical shuffle scans; hardware ds_min_u64; quad-jump pointer jumping (2 barriers/pass).
__global__ __launch_bounds__(1024) void k5_tree(const u64* __restrict__ keys,
                                                int* __restrict__ meta_g, int* __restrict__ level_start_g,
                                                int* __restrict__ maxd_g, int* __restrict__ lmin_g){
  const int b = blockIdx.x;
  const int tid = threadIdx.x;
  __shared__ u64 s_best[4096];           // 32 KB ; later: arr u32[8192] (packed succ|dist) / pfx short[8192] / hist u32[4096]
  __shared__ u32 s_comp[4096];           // 16 KB ; later: s_t u16[8064] / depth u16[4096]+parent u16[4096]
  __shared__ unsigned char s_mst[NE];    // 8 KB  ; bit0 = tree edge
  __shared__ u32 s_wt[16];               // cross-wave scan partials
  __shared__ volatile int s_flag;
  __shared__ volatile int s_flag2[2];    // double-buffered jump flags
  __shared__ volatile u32 s_maxd;

  u32* arr    = (u32*)s_best;             // 8192 u32 (32 KB)
  short* pfx  = (short*)s_best;           // 8192 short (first 16 KB)
  u16* s_t    = (u16*)s_comp;             // 8064 u16
  u16* s_dep  = (u16*)s_comp;             // final: 4096 u16
  u16* s_parr = ((u16*)s_comp) + 4096;    // final: 4096 u16
  u32* cnt32  = (u32*)s_best;             // final hist: 4096 u32 (first 16 KB)

  const int lane = tid & 63, wid = tid >> 6;

  u64 mykey[8];
  #pragma unroll
  for (int k=0;k<8;++k){ int e = tid + (k<<10); mykey[k] = (e < NE) ? keys[b*NE + e] : ~0ull; }

  for (int i=tid;i<4096;i+=1024){ s_comp[i] = i; lmin_g[b*4096+i] = 0x7FFFFFFF; }
  for (int e=tid;e<NE;e+=1024) s_mst[e] = 0;
  __syncthreads();

  // ---- Boruvka rounds (winner-flag early exit) ----
  for (int round=0; round<14; ++round){
    for (int i=tid;i<4096;i+=1024) s_best[i] = ~0ull;
    if (tid==0) s_flag = 0;
    __syncthreads();
    #pragma unroll
    for (int k=0;k<8;++k){
      int e = tid + (k<<10);
      if (e < NE){
        int u,v; edge_uv(e,u,v);
        u32 ru = s_comp[u], rv = s_comp[v];
        if (ru != rv){
          atomicMin((u64*)&s_best[ru], mykey[k]);   // hardware ds_min_u64, order-independent
          atomicMin((u64*)&s_best[rv], mykey[k]);
        }
      }
    }
    __syncthreads();
    u32 np4[4]; int any = 0;
    #pragma unroll
    for (int t=0;t<4;++t){
      int i = tid + (t<<10);
      np4[t] = s_comp[i];
      if (s_comp[i] == (u32)i && s_best[i] != ~0ull){
        int e = (int)(s_best[i] & 0x1FFFull);
        int u,v; edge_uv(e,u,v);
        u32 ru = s_comp[u], rv = s_comp[v];
        u32 s = (ru == (u32)i) ? rv : ru;
        s_mst[e] = 1; any = 1;
        bool mutual = ((s_best[s] & 0x1FFFull) == (u64)e);
        if (!mutual || (u32)i > s) np4[t] = s;   // mutual pair: smaller id stays root
      }
    }
    if (any) s_flag = 1;
    __syncthreads();
    int fl = s_flag;
    #pragma unroll
    for (int t=0;t<4;++t){ int i = tid + (t<<10); s_comp[i] = np4[t]; }
    if (tid==0){ s_flag2[0] = 0; s_flag2[1] = 0; }
    __syncthreads();
    if (!fl) break;
    // quad-jump pointer jumping until flat (2 barriers/pass)
    for (int pass=0; pass<14; ++pass){
      u32 t4[4]; int ch = 0;
      #pragma unroll
      for (int t=0;t<4;++t){
        int i = tid + (t<<10);
        u32 a = s_comp[i];
        u32 x = s_comp[a]; x = s_comp[x]; x = s_comp[x];
        t4[t] = x; if (x != a) ch = 1;
      }
      __syncthreads();                             // reads complete before writes
      #pragma unroll
      for (int t=0;t<4;++t){ int i = tid + (t<<10); s_comp[i] = t4[t]; }
      if (ch) s_flag2[pass&1] = 1;
      if (tid==0) s_flag2[(pass+1)&1] = 0;         // reset other buffer for next pass
      __syncthreads();                             // writes + flags visible
      if (!s_flag2[pass&1]) break;
    }
  }

  // ---- Euler tour: compact arc ids via hierarchical prefix-sum of tree-edge flags ----
  for (int i=tid;i<8192;i+=1024) arr[i] = (i<NE && s_mst[i]) ? 1u : 0u;
  __syncthreads();
  {
    u32 v[8];
    #pragma unroll
    for (int j=0;j<8;++j) v[j] = arr[tid*8+j];
    #pragma unroll
    for (int j=1;j<8;++j) v[j] += v[j-1];
    u32 mytot = v[7];
    u32 inc = mytot;
    #pragma unroll
    for (int o=1;o<64;o<<=1){ u32 n = __shfl_up(inc,o); if (lane>=o) inc += n; }
    if (lane==63) s_wt[wid] = inc;
    __syncthreads();
    if (tid<16){
      u32 x = s_wt[tid];
      #pragma unroll
      for (int o=1;o<16;o<<=1){ u32 n = __shfl_up(x,o); if (tid>=o) x += n; }
      s_wt[tid] = x;
    }
    __syncthreads();
    u32 tb = ((wid>0)? s_wt[wid-1] : 0u) + (inc - mytot);
    #pragma unroll
    for (int j=0;j<8;++j) arr[tid*8+j] = v[j] + tb;
  }
  __syncthreads();
  for (int e=tid;e<NE;e+=1024) s_t[e] = (u16)(arr[e] - (s_mst[e]?1u:0u));
  __syncthreads();

  // successor of arc (w->v): next outgoing arc of v after (v->w) in fixed dir order; cut at root 0
  auto nextarc = [&](int v, int w) -> int {
    int nb[4], eg[4]; int deg=0;
    int r=v>>6, c=v&63;
    if (c>0  && (s_mst[r*63+c-1]&1)){ nb[deg]=v-1;  eg[deg]=r*63+c-1; ++deg; }
    if (c<63 && (s_mst[r*63+c]&1))  { nb[deg]=v+1;  eg[deg]=r*63+c;   ++deg; }
    if (r>0  && (s_mst[NEH+v-64]&1)){ nb[deg]=v-64; eg[deg]=NEH+v-64; ++deg; }
    if (r<63 && (s_mst[NEH+v]&1))  { nb[deg]=v+64; eg[deg]=NEH+v;    ++deg; }
    int j=0;
    for (int k2=0;k2<deg;++k2) if (nb[k2]==w) j=k2;
    int jn=j+1;
    if (jn==deg){ if (v==0) return SENT; jn=0; }
    int e2=eg[jn], w2=nb[jn];
    return 2*(int)s_t[e2] + ((v<w2)?0:1);
  };

  // build packed (succ<<16)|dist; non-tree arcs self-loop with dist 0
  __syncthreads();
  for (int i=tid;i<8192;i+=1024) arr[i] = ((u32)i << 16);
  __syncthreads();
  for (int e=tid;e<NE;e+=1024){
    if (s_mst[e]&1){
      int t=s_t[e], u,v; edge_uv(e,u,v);
      arr[2*t]   = ((u32)nextarc(v,u) << 16) | 1u;   // arc u->v (head v)
      arr[2*t+1] = ((u32)nextarc(u,v) << 16) | 1u;   // arc v->u (head u)
    }
  }
  __syncthreads();

  // Wyllie (single pass, packed): dist-to-end in low 16, succ in high 16
  u32 reg8[8];
  #pragma unroll
  for (int k=0;k<8;++k) reg8[k] = arr[tid+(k<<10)];
  for (int rd=0; rd<13; ++rd){
    u32 o8[8];
    #pragma unroll
    for (int k=0;k<8;++k) o8[k] = arr[reg8[k] >> 16];
    __syncthreads();
    #pragma unroll
    for (int k=0;k<8;++k){
      reg8[k] = (o8[k] & 0xFFFF0000u) | ((reg8[k] + o8[k]) & 0xFFFFu);
      arr[tid+(k<<10)] = reg8[k];
    }
    __syncthreads();
  }

  // per-edge: down-arc = earlier in tour (larger dist); positions pos = m - dist
  const int m = 8190;
  u32 pk[8]; int has[8];
  #pragma unroll
  for (int k=0;k<8;++k){
    int e = tid + (k<<10); has[k] = 0;
    if (e < NE && (s_mst[e]&1)){
      int t = s_t[e];
      int d0 = (int)(arr[2*t] & 0xFFFFu), d1 = (int)(arr[2*t+1] & 0xFFFFu);
      int down = (d0 > d1) ? 1 : 0;               // 1: arc (u->v) is the down arc
      int posD = m - (down ? d0 : d1);
      int posU = m - (down ? d1 : d0);
      pk[k] = (u32)posD | ((u32)posU << 13) | ((u32)down << 26);
      has[k] = 1;
    }
  }
  __syncthreads();   // all reads of arr done before scatter overwrites region

  // scatter +/-1 by tour position into short[8192]; positions 0..8189 covered bijectively
  if (tid < 2) pfx[8190 + tid] = 0;
  #pragma unroll
  for (int k=0;k<8;++k){
    if (has[k]){
      pfx[pk[k] & 0x1FFFu] = 1;
      pfx[(pk[k] >> 13) & 0x1FFFu] = -1;
    }
  }
  __syncthreads();
  // hierarchical inclusive scan over short[8192] (int accumulation, exact)
  {
    int v[8];
    #pragma unroll
    for (int j=0;j<8;++j) v[j] = (int)pfx[tid*8+j];
    #pragma unroll
    for (int j=1;j<8;++j) v[j] += v[j-1];
    int mytot = v[7];
    int inc = mytot;
    #pragma unroll
    for (int o=1;o<64;o<<=1){ int n = __shfl_up(inc,o); if (lane>=o) inc += n; }
    if (lane==63) s_wt[wid] = (u32)inc;
    __syncthreads();
    if (tid<16){
      int x = (int)s_wt[tid];
      #pragma unroll
      for (int o=1;o<16;o<<=1){ int n = __shfl_up(x,o); if (tid>=o) x += n; }
      s_wt[tid] = (u32)x;
    }
    __syncthreads();
    int tb = ((wid>0)? (int)s_wt[wid-1] : 0) + (inc - mytot);
    #pragma unroll
    for (int j=0;j<8;++j) pfx[tid*8+j] = (short)(v[j] + tb);
  }
  __syncthreads();

  // depth[child] = inclusive prefix at down-arc position; parent from orientation
  int chld[8], prnt[8], dpv[8];
  #pragma unroll
  for (int k=0;k<8;++k){
    int e = tid + (k<<10); chld[k] = -1;
    if (has[k]){
      int u,v; edge_uv(e,u,v);
      int down = (pk[k] >> 26) & 1;
      chld[k] = down ? v : u;
      prnt[k] = down ? u : v;
      dpv[k]  = (int)pfx[pk[k] & 0x1FFFu];
    }
  }
  __syncthreads();   // all reads of s_t/pfx done before overwriting s_comp region
  #pragma unroll
  for (int k=0;k<8;++k) if (chld[k]>=0){ s_dep[chld[k]]=(u16)dpv[k]; s_parr[chld[k]]=(u16)prnt[k]; }
  if (tid==0){ s_dep[0]=0; s_parr[0]=0; }
  __syncthreads();

  // ---- level histogram + min-node + scan + level-ordered meta scatter ----
  for (int i=tid;i<4096;i+=1024) cnt32[i] = 0;
  if (tid==0) s_maxd = 0;
  __syncthreads();
  #pragma unroll
  for (int t=0;t<4;++t){
    int i = (tid<<2) + t;
    u32 dd = s_dep[i];
    atomicAdd(&cnt32[dd], 1u);
    atomicMax((u32*)&s_maxd, dd);
    atomicMin(&lmin_g[b*4096 + (int)dd], i);
  }
  __syncthreads();
  int md = (int)s_maxd;
  // hierarchical inclusive scan over cnt32[4096]
  {
    u32 v[4];
    #pragma unroll
    for (int j=0;j<4;++j) v[j] = cnt32[tid*4+j];
    #pragma unroll
    for (int j=1;j<4;++j) v[j] += v[j-1];
    u32 mytot = v[3];
    u32 inc = mytot;
    #pragma unroll
    for (int o=1;o<64;o<<=1){ u32 n = __shfl_up(inc,o); if (lane>=o) inc += n; }
    if (lane==63) s_wt[wid] = inc;
    __syncthreads();
    if (tid<16){
      u32 x = s_wt[tid];
      #pragma unroll
      for (int o=1;o<16;o<<=1){ u32 n = __shfl_up(x,o); if (tid>=o) x += n; }
      s_wt[tid] = x;
    }
    __syncthreads();
    u32 tb = ((wid>0)? s_wt[wid-1] : 0u) + (inc - mytot);
    #pragma unroll
    for (int j=0;j<4;++j) cnt32[tid*4+j] = v[j] + tb;
  }
  __syncthreads();
  for (int i=tid; i<4097; i+=1024){
    int ls = (i==0) ? 0 : (int)cnt32[i-1];
    level_start_g[b*4104 + i] = ls;
  }
  u32 ex4[4];
  #pragma unroll
  for (int t=0;t<4;++t){ int i = tid + (t<<10); ex4[t] = (i==0) ? 0u : cnt32[i-1]; }
  __syncthreads();
  #pragma unroll
  for (int t=0;t<4;++t){ int i = tid + (t<<10); cnt32[i] = ex4[t]; }
  __syncthreads();
  #pragma unroll
  for (int t=0;t<4;++t){
    int i = (tid<<2) + t;
    u32 pos = atomicAdd(&cnt32[s_dep[i]], 1u);
    meta_g[b*4096 + (int)pos] = i | ((int)s_parr[i] << 16);   // v | parent<<16, level-ordered
  }
  if (tid==0) maxd_g[b] = md;
}

// ---------------- K5b: mark pad-keeper nodes: bit 12 of meta on the lmin node of padded levels ----------------
__global__ __launch_bounds__(256) void k5b_mark(const int* __restrict__ lstart, const int* __restrict__ lmin_g,
                                                int* __restrict__ meta_g){
  int d = blockIdx.x*256 + threadIdx.x;
  if (d == 0 || d >= 4096) return;
  int cnts[NB]; int mx = 0;
  #pragma unroll
  for (int b=0;b<NB;++b){
    int c = lstart[b*4104 + d + 1] - lstart[b*4104 + d];
    cnts[b] = c; if (c > mx) mx = c;
  }
  #pragma unroll
  for (int b=0;b<NB;++b){
    if (cnts[b] > 0 && cnts[b] < mx){
      int keeper = lmin_g[b*4096 + d];
      int st = lstart[b*4104 + d];
      for (int p2=st; p2<st+cnts[b]; ++p2){
        int idx = b*4096 + p2;
        if ((meta_g[idx] & 4095) == keeper){ meta_g[idx] |= 0x1000; break; }
      }
    }
  }
}

// ---------------- K5c: permute ew into LEVEL order per (b,ch), in place via LDS staging ----------------
__global__ __launch_bounds__(256) void k5c_permute(const int* __restrict__ meta_g, float* __restrict__ ew_cm){
  __shared__ float se[4096];
  const int bid = blockIdx.x;
  const int b = bid / ND, ch = bid - b*ND;
  float* ewc = ew_cm + ((size_t)(b*ND + ch))*NL;
  const int* mg = meta_g + b*4096;
  for (int i=threadIdx.x; i<1024; i+=256) ((float4*)se)[i] = ((const float4*)ewc)[i];
  __syncthreads();
  for (int p=threadIdx.x; p<NL; p+=256) ewc[p] = se[mg[p] & 4095];
}

// ---------------- K6: LDS-resident tree scan, one wave per (batch, channel); CM output ----------------
// R1 structure + R11: second prefetched chunk per level (lanes 64..127 in registers) so levels with
// 64 < c <= 128 avoid the blocking tail loads; c > 128 falls back to the loop (rare). Per-lane
// instruction order identical to the 1-chunk version -> FP-exact.
__global__ __launch_bounds__(64) void k6_scan(const float* __restrict__ ewlo_cm, const float* __restrict__ up_cm,
                                              float* __restrict__ aggr_cm, const int* __restrict__ meta_g,
                                              const int* __restrict__ lstart, const int* __restrict__ maxd_g){
  __shared__ float s_ua[4096];      // BX -> up -> aggr (in-place), 16 KB
  __shared__ u64   s_ls64[1026];    // level starts as u16[4104], 8.2 KB (u64-aligned for packed writes)
  u16* s_ls = (u16*)s_ls64;
  const int bid = blockIdx.x;
  const int b = bid / ND, ch = bid - b*ND;
  const int lane = threadIdx.x;
  const int md = maxd_g[b];
  const float* el = ewlo_cm + ((size_t)(b*ND + ch))*NL;   // ew in LEVEL order
  const float* upc = up_cm + ((size_t)(b*ND + ch))*NL;
  const int* mg = meta_g + b*4096;

  // stage level starts (vectorized: int4 global read -> 4x u16 packed into one b64 LDS write)
  {
    const int4* ls4 = (const int4*)(lstart + b*4104);
    int n4 = (md + 2 + 3) >> 2;              // entries 0..md+1 needed
    for (int i=lane; i<n4; i+=64){
      int4 t = ls4[i];
      u64 pkv = (u64)(u16)t.x | ((u64)(u16)t.y<<16) | ((u64)(u16)t.z<<32) | ((u64)(u16)t.w<<48);
      s_ls64[i] = pkv;
    }
  }
  // stage BX
  for (int i=lane; i<1024; i+=64) ((float4*)s_ua)[i] = ((const float4*)upc)[i];

  // 8-slot rolling pipeline state, 2 chunks per slot (static indices only)
  #define K6_DECL(k) int stS##k=0, cS##k=0, mS##k=0, mT##k=0; float wS##k=0.f, wT##k=0.f;
  K6_DECL(0) K6_DECL(1) K6_DECL(2) K6_DECL(3) K6_DECL(4) K6_DECL(5) K6_DECL(6) K6_DECL(7)

  // ---- up-sweep: levels md..1 ----
  #define K6_LOADU(k, dexpr) { int dd_=(dexpr); cS##k=0; if (dd_>=1){ \
      stS##k=(int)s_ls[dd_]; cS##k=(int)s_ls[dd_+1]-stS##k; \
      if (lane<cS##k){ mS##k=mg[stS##k+lane]; wS##k=el[stS##k+lane]; } \
      if (lane+64<cS##k){ mT##k=mg[stS##k+64+lane]; wT##k=el[stS##k+64+lane]; } } }
  #define K6_PROCU(k) { if (lane<cS##k){ \
      int v_=mS##k&4095, p_=(mS##k>>16)&4095; \
      atomicAdd(&s_ua[p_], wS##k*s_ua[v_]); } \
    if (lane+64<cS##k){ \
      int v_=mT##k&4095, p_=(mT##k>>16)&4095; \
      atomicAdd(&s_ua[p_], wT##k*s_ua[v_]); } \
    for (int i_=lane+128;i_<cS##k;i_+=64){ \
      int m_=mg[stS##k+i_]; float ww_=el[stS##k+i_]; \
      int v_=m_&4095, p_=(m_>>16)&4095; \
      atomicAdd(&s_ua[p_], ww_*s_ua[v_]); } }

  K6_LOADU(0, md)   K6_LOADU(1, md-1) K6_LOADU(2, md-2) K6_LOADU(3, md-3)
  K6_LOADU(4, md-4) K6_LOADU(5, md-5) K6_LOADU(6, md-6) K6_LOADU(7, md-7)
  for (int base = md; base >= 1; base -= 8){
    K6_PROCU(0) K6_PROCU(1) K6_PROCU(2) K6_PROCU(3)
    K6_PROCU(4) K6_PROCU(5) K6_PROCU(6) K6_PROCU(7)
    K6_LOADU(0, base-8)  K6_LOADU(1, base-9)  K6_LOADU(2, base-10) K6_LOADU(3, base-11)
    K6_LOADU(4, base-12) K6_LOADU(5, base-13) K6_LOADU(6, base-14) K6_LOADU(7, base-15)
  }

  // ---- down-sweep: levels 1..md, same pipelining; pad keeper via bit 12 of meta ----
  #define K6_LOADD(k, dexpr) { int dd_=(dexpr); cS##k=0; if (dd_<=md){ \
      stS##k=(int)s_ls[dd_]; cS##k=(int)s_ls[dd_+1]-stS##k; \
      if (lane<cS##k){ mS##k=mg[stS##k+lane]; wS##k=el[stS##k+lane]; } \
      if (lane+64<cS##k){ mT##k=mg[stS##k+64+lane]; wT##k=el[stS##k+64+lane]; } } }
  #define K6_PROCD(k) { if (lane<cS##k){ \
      int m_=mS##k; float ww_=wS##k; \
      int v_=m_&4095, p_=(m_>>16)&4095; \
      float uv_=s_ua[v_]; \
      float r_=uv_+ww_*(s_ua[p_]-ww_*uv_); \
      if (m_&0x1000) r_=uv_; \
      s_ua[v_]=r_; } \
    if (lane+64<cS##k){ \
      int m_=mT##k; float ww_=wT##k; \
      int v_=m_&4095, p_=(m_>>16)&4095; \
      float uv_=s_ua[v_]; \
      float r_=uv_+ww_*(s_ua[p_]-ww_*uv_); \
      if (m_&0x1000) r_=uv_; \
      s_ua[v_]=r_; } \
    for (int i_=lane+128;i_<cS##k;i_+=64){ \
      int m_=mg[stS##k+i_]; float ww_=el[stS##k+i_]; \
      int v_=m_&4095, p_=(m_>>16)&4095; \
      float uv_=s_ua[v_]; \
      float r_=uv_+ww_*(s_ua[p_]-ww_*uv_); \
      if (m_&0x1000) r_=uv_; \
      s_ua[v_]=r_; } }

  K6_LOADD(0, 1) K6_LOADD(1, 2) K6_LOADD(2, 3) K6_LOADD(3, 4)
  K6_LOADD(4, 5) K6_LOADD(5, 6) K6_LOADD(6, 7) K6_LOADD(7, 8)
  for (int base = 1; base <= md; base += 8){
    K6_PROCD(0) K6_PROCD(1) K6_PROCD(2) K6_PROCD(3)
    K6_PROCD(4) K6_PROCD(5) K6_PROCD(6) K6_PROCD(7)
    K6_LOADD(0, base+8)  K6_LOADD(1, base+9)  K6_LOADD(2, base+10) K6_LOADD(3, base+11)
    K6_LOADD(4, base+12) K6_LOADD(5, base+13) K6_LOADD(6, base+14) K6_LOADD(7, base+15)
  }

  #undef K6_DECL
  #undef K6_LOADU
  #undef K6_PROCU
  #undef K6_LOADD
  #undef K6_PROCD

  // write back CHANNEL-MAJOR: contiguous 16 KB per block, float4, fully coalesced full lines
  float* outc = aggr_cm + ((size_t)(b*ND + ch))*NL;
  for (int i=lane; i<1024; i+=64) ((float4*)outc)[i] = ((const float4*)s_ua)[i];
}

// ---------------- K7+K8 fused: LN(h)*Cs + Ds*xs -> LN -> *z -> GEMM @ out_proj_w.T ----------------
__global__ __launch_bounds__(256) void k7k8(const float* __restrict__ aggr_cm, const float* __restrict__ xs,
                                            const float* __restrict__ z, const float* __restrict__ Cs,
                                            const float* __restrict__ Dsw, const float* __restrict__ hg,
                                            const float* __restrict__ hb, const float* __restrict__ og,
                                            const float* __restrict__ ob, const float* __restrict__ w2,
                                            float* __restrict__ out){
  __shared__ float tile[192*33];    // phase1: h [d][lcol]; phase2: y [k][row] (same layout)
  __shared__ float sw[96*97];       // w2 chunk transposed [k][o0..95]
  const int b  = blockIdx.x >> 7;          // 8 batches
  const int l0 = (blockIdx.x & 127) * 32;  // 128 tiles of 32 rows
  const int tid = threadIdx.x;

  for (int i=tid; i<192*32; i+=256){
    int ch = i >> 5, lcol = i & 31;
    tile[ch*33 + lcol] = aggr_cm[((size_t)(b*ND + ch))*NL + l0 + lcol];
  }
  __syncthreads();

  const int wv = tid >> 6, lane = tid & 63;
  float yv[8][3];
  for (int s=0; s<8; ++s){
    int lcol = wv*8 + s;
    int gid = b*NL + l0 + lcol;
    float h[3], x3[3], z3[3];
    #pragma unroll
    for (int j=0;j<3;++j){
      int d = lane + 64*j;
      h[j]  = tile[d*33 + lcol];
      x3[j] = xs[(size_t)gid*ND + d];
      z3[j] = z[(size_t)gid*ND + d];
    }
    float mu  = wred_f(h[0]+h[1]+h[2]) / 192.f;
    float vs = 0.f;
    #pragma unroll
    for (int j=0;j<3;++j){ float t = h[j]-mu; vs += t*t; }
    float inv = 1.f / sqrtf(wred_f(vs)/192.f + 1e-5f);
    float Cv = Cs[gid];
    float y[3];
    #pragma unroll
    for (int j=0;j<3;++j){
      int d = lane + 64*j;
      float hn = (h[j]-mu)*inv*hg[d] + hb[d];
      y[j] = hn*Cv + Dsw[d]*x3[j];
    }
    float mu2 = wred_f(y[0]+y[1]+y[2]) / 192.f;
    float vs2 = 0.f;
    #pragma unroll
    for (int j=0;j<3;++j){ float t = y[j]-mu2; vs2 += t*t; }
    float inv2 = 1.f / sqrtf(wred_f(vs2)/192.f + 1e-5f);
    #pragma unroll
    for (int j=0;j<3;++j){
      int d = lane + 64*j;
      float o = (y[j]-mu2)*inv2*og[d] + ob[d];
      yv[s][j] = o*z3[j];
    }
  }
  __syncthreads();             // all h reads done
  #pragma unroll
  for (int s=0; s<8; ++s){
    int lcol = wv*8 + s;
    #pragma unroll
    for (int j=0;j<3;++j){
      int d = lane + 64*j;
      tile[d*33 + lcol] = yv[s][j];   // y into same slot/layout
    }
  }

  // ---- GEMM phase: out[32 x 96] = y[32 x 192] @ w2^T, K split 2x96 (bit-identical to old k8) ----
  const int rq = tid >> 5;          // 0..7 -> rows rq*4..rq*4+3
  const int cq = tid & 31;          // 0..31 -> cols cq*3..cq*3+2
  float acc[4][3];
  #pragma unroll
  for (int a=0;a<4;++a)
    #pragma unroll
    for (int bcl=0;bcl<3;++bcl) acc[a][bcl] = 0.f;

  for (int kc=0; kc<2; ++kc){
    __syncthreads();
    for (int i=tid; i<96*96; i+=256){
      int o = i/96, k = i - o*96;
      sw[k*97 + o] = w2[(size_t)o*ND + kc*96 + k];
    }
    __syncthreads();
    #pragma unroll 4
    for (int k=0;k<96;++k){
      float4 ya = *(const float4*)&tile[(kc*96 + k)*33 + rq*4];
      float w0 = sw[k*97 + cq*3 + 0];
      float w1 = sw[k*97 + cq*3 + 1];
      float wvv = sw[k*97 + cq*3 + 2];
      acc[0][0] += ya.x*w0; acc[0][1] += ya.x*w1; acc[0][2] += ya.x*wvv;
      acc[1][0] += ya.y*w0; acc[1][1] += ya.y*w1; acc[1][2] += ya.y*wvv;
      acc[2][0] += ya.z*w0; acc[2][1] += ya.z*w1; acc[2][2] += ya.z*wvv;
      acc[3][0] += ya.w*w0; acc[3][1] += ya.w*w1; acc[3][2] += ya.w*wvv;
    }
  }

  #pragma unroll
  for (int a=0;a<4;++a){
    size_t row = (size_t)b*NL + l0 + rq*4 + a;
    #pragma unroll
    for (int bcl=0;bcl<3;++bcl){
      out[row*NDM + cq*3 + bcl] = acc[a][bcl];
    }
  }
}

extern "C" void kernel_launch(void* const* d_in, const int* in_sizes, int n_in,
                              void* d_out, int out_size, void* d_ws, size_t ws_size,
                              hipStream_t stream){
  const float* x    = (const float*)d_in[0];
  const float* inw  = (const float*)d_in[1];
  const float* cw   = (const float*)d_in[2];
  const float* cb   = (const float*)d_in[3];
  const float* xpw  = (const float*)d_in[4];
  const float* dtw  = (const float*)d_in[5];
  const float* dtb  = (const float*)d_in[6];
  const float* alog = (const float*)d_in[7];
  const float* Dsw  = (const float*)d_in[8];
  const float* hg   = (const float*)d_in[9];
  const float* hb   = (const float*)d_in[10];
  const float* og   = (const float*)d_in[11];
  const float* ob   = (const float*)d_in[12];
  const float* w2   = (const float*)d_in[13];
  float* out = (float*)d_out;

  const size_t S = (size_t)NB*NL*ND;   // 6,291,456 elems per f32 buffer
  float* bufA  = (float*)d_ws;         // xc_pre
  float* bufZ  = bufA + S;             // silu(z)
  float* bufX  = bufZ + S;             // xs (post-conv silu)
  float* ew_cm = bufX + S;             // deltaA, channel-major; k5c permutes to LEVEL order in place
  float* up_cm = ew_cm + S;            // BX, channel-major [b][d][l]
  float* bufG  = up_cm + S;            // aggr, channel-major [b][d][l]
  char* q = (char*)(bufG + S);
  double* norms = (double*)q;                q += (size_t)NB*NL*sizeof(double);
  u64* keys     = (u64*)q;                   q += (size_t)NB*NE*sizeof(u64);
  float* Cs     = (float*)q;                 q += (size_t)NB*NL*sizeof(float);
  int* lstart   = (int*)q;                   q += (size_t)NB*4104*sizeof(int);
  int* maxd     = (int*)q;                   q += 64*sizeof(int);
  int* lmin     = (int*)q;                   q += (size_t)NB*NL*sizeof(int);
  int* meta     = (int*)q;                   q += (size_t)NB*NL*sizeof(int);

  k1_inproj<<<dim3(NB*NL/32*4), dim3(256), 0, stream>>>(x, inw, bufA, bufZ);
  k2_conv  <<<dim3((NB*NL*ND)/256), dim3(256), 0, stream>>>(bufA, cw, cb, bufX);
  k3_ssm   <<<dim3(NB*NL/16), dim3(1024), 0, stream>>>(bufX, xpw, dtw, dtb, alog, ew_cm, up_cm, Cs, norms);
  k4_keys  <<<dim3(NB*NE/4), dim3(256), 0, stream>>>(bufX, norms, keys);
  k5_tree  <<<dim3(NB), dim3(1024), 0, stream>>>(keys, meta, lstart, maxd, lmin);
  k5b_mark <<<dim3(16), dim3(256), 0, stream>>>(lstart, lmin, meta);
  k5c_permute<<<dim3(NB*ND), dim3(256), 0, stream>>>(meta, ew_cm);
  k6_scan  <<<dim3(NB*ND), dim3(64), 0, stream>>>(ew_cm, up_cm, bufG, meta, lstart, maxd);
  k7k8     <<<dim3(NB*128), dim3(256), 0, stream>>>(bufG, bufX, bufZ, Cs, Dsw, hg, hb, og, ob, w2, out);
}

// Round 12
// 570.900 us; speedup vs baseline: 1.0553x; 1.0553x over previous
//
#include <hip/hip_runtime.h>
#include <hip/hip_bf16.h>
#include <cstdint>

typedef unsigned long long u64;
typedef unsigned int u32;
typedef unsigned short u16;

constexpr int NB   = 8;     // batch
constexpr int NL   = 4096;  // H*W
constexpr int ND   = 192;   // D_INNER
constexpr int NDM  = 96;    // D_MODEL
constexpr int NE   = 8064;  // edges per batch
constexpr int NEH  = 4032;  // horizontal edges
constexpr int SENT = 8190;  // Euler sentinel (m = 2*4095)

__device__ __forceinline__ float siluf(float x){ return x / (1.f + expf(-x)); }
__device__ __forceinline__ float softplusf(float x){ return fmaxf(x,0.f) + log1pf(expf(-fabsf(x))); }

__device__ __forceinline__ float wred_f(float v){
  #pragma unroll
  for (int o=32;o;o>>=1) v += __shfl_down(v,o);
  return __shfl(v,0);
}
__device__ __forceinline__ double wred_d(double v){
  #pragma unroll
  for (int o=32;o;o>>=1) v += __shfl_down(v,o);
  return __shfl(v,0);
}

// edge e -> endpoints (reference ordering: horizontal first, row-major, then vertical); u < v always
__device__ __forceinline__ void edge_uv(int e, int& u, int& v){
  if (e < NEH){ int r=e/63; int c=e-r*63; u=(r<<6)+c; v=u+1; }
  else        { u=e-NEH; v=u+64; }
}

// ---------------- K1: xz = x @ in_proj_w.T (f32, LDS-tiled); split -> xc_pre, z=silu ----------------
__global__ __launch_bounds__(256) void k1_inproj(const float* __restrict__ x, const float* __restrict__ w,
                                                 float* __restrict__ xc_pre, float* __restrict__ zb){
  __shared__ float sx[96*33];       // [k][row0..31], pad 33
  __shared__ float sw[96*97];       // [k][col0..95], pad 97
  const int tid = threadIdx.x;
  const int brow = blockIdx.x >> 2;
  const int cc   = blockIdx.x & 3;
  const int row0 = brow * 32;
  {
    const float* src = x + (size_t)row0*96;
    for (int i=tid; i<32*96; i+=256){
      int r = i/96, k = i - r*96;
      sx[k*33 + r] = src[i];
    }
  }
  {
    const float* src = w + (size_t)cc*96*96;
    for (int i=tid; i<96*96; i+=256){
      int c = i/96, k = i - c*96;
      sw[k*97 + c] = src[i];
    }
  }
  __syncthreads();
  const int rq = tid >> 5;
  const int cq = tid & 31;
  float acc[4][3];
  #pragma unroll
  for (int a=0;a<4;++a)
    #pragma unroll
    for (int bcl=0;bcl<3;++bcl) acc[a][bcl] = 0.f;
  #pragma unroll 4
  for (int k=0;k<96;++k){
    float4 xa = *(const float4*)&sx[k*33 + rq*4];
    float w0 = sw[k*97 + cq*3 + 0];
    float w1 = sw[k*97 + cq*3 + 1];
    float w2 = sw[k*97 + cq*3 + 2];
    acc[0][0] += xa.x*w0; acc[0][1] += xa.x*w1; acc[0][2] += xa.x*w2;
    acc[1][0] += xa.y*w0; acc[1][1] += xa.y*w1; acc[1][2] += xa.y*w2;
    acc[2][0] += xa.z*w0; acc[2][1] += xa.z*w1; acc[2][2] += xa.z*w2;
    acc[3][0] += xa.w*w0; acc[3][1] += xa.w*w1; acc[3][2] += xa.w*w2;
  }
  #pragma unroll
  for (int a=0;a<4;++a){
    size_t row = row0 + rq*4 + a;
    #pragma unroll
    for (int bcl=0;bcl<3;++bcl){
      int c = cq*3 + bcl;
      float v = acc[a][bcl];
      if (cc < 2) xc_pre[row*ND + cc*96 + c] = v;
      else        zb[row*ND + (cc-2)*96 + c] = siluf(v);
    }
  }
}

// ---------------- K2: depthwise 3x3 conv (SAME) + bias + silu (f32) -> xs ----------------
__global__ __launch_bounds__(256) void k2_conv(const float* __restrict__ xc_pre, const float* __restrict__ cw,
                                               const float* __restrict__ cb, float* __restrict__ xs){
  int idx = blockIdx.x*256 + threadIdx.x;
  if (idx >= NB*NL*ND) return;
  int d = idx % ND;
  int l = (idx/ND) & 4095;
  int b = idx / (ND*NL);
  int r = l >> 6, c = l & 63;
  float acc = cb[d];
  #pragma unroll
  for (int dy=-1; dy<=1; ++dy){
    int rr = r+dy; if (rr<0 || rr>63) continue;
    #pragma unroll
    for (int dx=-1; dx<=1; ++dx){
      int cc = c+dx; if (cc<0 || cc>63) continue;
      acc += xc_pre[((size_t)b*NL + (rr<<6) + cc)*ND + d] * cw[d*9 + (dy+1)*3 + (dx+1)];
    }
  }
  xs[idx] = siluf(acc);
}

// ---------------- K3: x_dbl dots, dts->softplus, ew/BX channel-major via LDS write-batching ----------------
__global__ __launch_bounds__(1024) void k3_ssm(const float* __restrict__ xs, const float* __restrict__ xpw,
                                               const float* __restrict__ dtw, const float* __restrict__ dtb,
                                               const float* __restrict__ alog,
                                               float* __restrict__ ew_cm, float* __restrict__ up_cm,
                                               float* __restrict__ Cs, double* __restrict__ norms){
  __shared__ float s_ew[192*17];    // [d][l0..15], pad 17 -> conflict-free
  __shared__ float s_up[192*17];
  const int wid  = threadIdx.x >> 6;            // 0..15: which l within the tile
  const int lane = threadIdx.x & 63;
  const int gid  = blockIdx.x*16 + wid;         // b*NL + l  (4096%16==0: no batch straddle)
  const int b    = gid >> 12;
  const float* xr = xs + (size_t)gid*ND;
  float xv[3];
  #pragma unroll
  for (int j=0;j<3;++j) xv[j] = xr[lane + 64*j];
  float sums[8];
  #pragma unroll
  for (int cc=0; cc<8; ++cc){
    float p = 0.f;
    #pragma unroll
    for (int j=0;j<3;++j) p += xv[j]*xpw[cc*ND + lane + 64*j];
    sums[cc] = wred_f(p);
  }
  double n2 = 0.0;
  #pragma unroll
  for (int j=0;j<3;++j) n2 += (double)xv[j]*(double)xv[j];
  n2 = wred_d(n2);
  if (lane==0){
    Cs[gid] = sums[7];
    norms[gid] = fmax(sqrt(n2), 1e-8);
  }
  float Bv = sums[6];
  #pragma unroll
  for (int j=0;j<3;++j){
    int d = lane + 64*j;
    float dtv = dtb[d];
    #pragma unroll
    for (int r=0;r<6;++r) dtv += sums[r]*dtw[d*6+r];
    float sp = softplusf(dtv);
    float A  = -expf(alog[d]);
    s_ew[d*17 + wid] = expf(sp*A);
    s_up[d*17 + wid] = sp*Bv*xv[j];   // BX = dts*Bs*xs
  }
  __syncthreads();
  // cooperative channel-major write: thread t -> (dd = t>>4, lq = t&15); full 64B line per dd
  const int dq = threadIdx.x >> 4;              // 0..63
  const int lq = threadIdx.x & 15;
  const int lb = (blockIdx.x*16) & 4095;        // l tile base within batch
  #pragma unroll
  for (int q=0;q<3;++q){
    int dd = dq + 64*q;
    size_t o = ((size_t)(b*ND + dd))*NL + lb + lq;
    ew_cm[o] = s_ew[dd*17 + lq];
    up_cm[o] = s_up[dd*17 + lq];
  }
}

// ---------------- K4: per-edge f64 normalized dot -> sortable u64 key ----------------
__global__ __launch_bounds__(256) void k4_keys(const float* __restrict__ xs, const double* __restrict__ norms,
                                               u64* __restrict__ keys){
  int gid = blockIdx.x*4 + (threadIdx.x>>6);   // one wave per (b,e)
  if (gid >= NB*NE) return;
  int lane = threadIdx.x & 63;
  int b = gid / NE, e = gid - b*NE;
  int u, v; edge_uv(e, u, v);
  const float* xu = xs + ((size_t)(b*NL + u))*ND;
  const float* xw = xs + ((size_t)(b*NL + v))*ND;
  double nu = norms[b*NL+u], nv = norms[b*NL+v];
  double dot = 0.0;
  #pragma unroll
  for (int j=0;j<3;++j){
    int d = lane + 64*j;
    double du = (double)xu[d] / nu;     // fn = f/norm per element, like reference
    double dv = (double)xw[d] / nv;
    dot += du*dv;
  }
  dot = wred_d(dot);
  if (lane==0){
    long long q = __double2ll_rn((1.0 - dot) * 17592186044416.0);  // 2^44
    if (q < 0) q = 0;
    keys[gid] = (((u64)q) << 13) | (u64)e;
  }
}

// ---------------- K5: Boruvka MST + Euler-tour depth/parent (single Wyllie + positional scan) ----------------
// Hierarchical shuffle scans; hardware ds_min_u64; quad-jump pointer jumping (2 barriers/pass).
__global__ __launch_bounds__(1024) void k5_tree(const u64* __restrict__ keys,
                                                int* __restrict__ meta_g, int* __restrict__ level_start_g,
                                                int* __restrict__ maxd_g, int* __restrict__ lmin_g){
  const int b = blockIdx.x;
  const int tid = threadIdx.x;
  __shared__ u64 s_best[4096];           // 32 KB ; later: arr u32[8192] (packed succ|dist) / pfx short[8192] / hist u32[4096]
  __shared__ u32 s_comp[4096];           // 16 KB ; later: s_t u16[8064] / depth u16[4096]+parent u16[4096]
  __shared__ unsigned char s_mst[NE];    // 8 KB  ; bit0 = tree edge
  __shared__ u32 s_wt[16];               // cross-wave scan partials
  __shared__ volatile int s_flag;
  __shared__ volatile int s_flag2[2];    // double-buffered jump flags
  __shared__ volatile u32 s_maxd;

  u32* arr    = (u32*)s_best;             // 8192 u32 (32 KB)
  short* pfx  = (short*)s_best;           // 8192 short (first 16 KB)
  u16* s_t    = (u16*)s_comp;             // 8064 u16
  u16* s_dep  = (u16*)s_comp;             // final: 4096 u16
  u16* s_parr = ((u16*)s_comp) + 4096;    // final: 4096 u16
  u32* cnt32  = (u32*)s_best;             // final hist: 4096 u32 (first 16 KB)

  const int lane = tid & 63, wid = tid >> 6;

  u64 mykey[8];
  #pragma unroll
  for (int k=0;k<8;++k){ int e = tid + (k<<10); mykey[k] = (e < NE) ? keys[b*NE + e] : ~0ull; }

  for (int i=tid;i<4096;i+=1024){ s_comp[i] = i; lmin_g[b*4096+i] = 0x7FFFFFFF; }
  for (int e=tid;e<NE;e+=1024) s_mst[e] = 0;
  __syncthreads();

  // ---- Boruvka rounds (winner-flag early exit) ----
  for (int round=0; round<14; ++round){
    for (int i=tid;i<4096;i+=1024) s_best[i] = ~0ull;
    if (tid==0) s_flag = 0;
    __syncthreads();
    #pragma unroll
    for (int k=0;k<8;++k){
      int e = tid + (k<<10);
      if (e < NE){
        int u,v; edge_uv(e,u,v);
        u32 ru = s_comp[u], rv = s_comp[v];
        if (ru != rv){
          atomicMin((u64*)&s_best[ru], mykey[k]);   // hardware ds_min_u64, order-independent
          atomicMin((u64*)&s_best[rv], mykey[k]);
        }
      }
    }
    __syncthreads();
    u32 np4[4]; int any = 0;
    #pragma unroll
    for (int t=0;t<4;++t){
      int i = tid + (t<<10);
      np4[t] = s_comp[i];
      if (s_comp[i] == (u32)i && s_best[i] != ~0ull){
        int e = (int)(s_best[i] & 0x1FFFull);
        int u,v; edge_uv(e,u,v);
        u32 ru = s_comp[u], rv = s_comp[v];
        u32 s = (ru == (u32)i) ? rv : ru;
        s_mst[e] = 1; any = 1;
        bool mutual = ((s_best[s] & 0x1FFFull) == (u64)e);
        if (!mutual || (u32)i > s) np4[t] = s;   // mutual pair: smaller id stays root
      }
    }
    if (any) s_flag = 1;
    __syncthreads();
    int fl = s_flag;
    #pragma unroll
    for (int t=0;t<4;++t){ int i = tid + (t<<10); s_comp[i] = np4[t]; }
    if (tid==0){ s_flag2[0] = 0; s_flag2[1] = 0; }
    __syncthreads();
    if (!fl) break;
    // quad-jump pointer jumping until flat (2 barriers/pass)
    for (int pass=0; pass<14; ++pass){
      u32 t4[4]; int ch = 0;
      #pragma unroll
      for (int t=0;t<4;++t){
        int i = tid + (t<<10);
        u32 a = s_comp[i];
        u32 x = s_comp[a]; x = s_comp[x]; x = s_comp[x];
        t4[t] = x; if (x != a) ch = 1;
      }
      __syncthreads();                             // reads complete before writes
      #pragma unroll
      for (int t=0;t<4;++t){ int i = tid + (t<<10); s_comp[i] = t4[t]; }
      if (ch) s_flag2[pass&1] = 1;
      if (tid==0) s_flag2[(pass+1)&1] = 0;         // reset other buffer for next pass
      __syncthreads();                             // writes + flags visible
      if (!s_flag2[pass&1]) break;
    }
  }

  // ---- Euler tour: compact arc ids via hierarchical prefix-sum of tree-edge flags ----
  for (int i=tid;i<8192;i+=1024) arr[i] = (i<NE && s_mst[i]) ? 1u : 0u;
  __syncthreads();
  {
    u32 v[8];
    #pragma unroll
    for (int j=0;j<8;++j) v[j] = arr[tid*8+j];
    #pragma unroll
    for (int j=1;j<8;++j) v[j] += v[j-1];
    u32 mytot = v[7];
    u32 inc = mytot;
    #pragma unroll
    for (int o=1;o<64;o<<=1){ u32 n = __shfl_up(inc,o); if (lane>=o) inc += n; }
    if (lane==63) s_wt[wid] = inc;
    __syncthreads();
    if (tid<16){
      u32 x = s_wt[tid];
      #pragma unroll
      for (int o=1;o<16;o<<=1){ u32 n = __shfl_up(x,o); if (tid>=o) x += n; }
      s_wt[tid] = x;
    }
    __syncthreads();
    u32 tb = ((wid>0)? s_wt[wid-1] : 0u) + (inc - mytot);
    #pragma unroll
    for (int j=0;j<8;++j) arr[tid*8+j] = v[j] + tb;
  }
  __syncthreads();
  for (int e=tid;e<NE;e+=1024) s_t[e] = (u16)(arr[e] - (s_mst[e]?1u:0u));
  __syncthreads();

  // successor of arc (w->v): next outgoing arc of v after (v->w) in fixed dir order; cut at root 0
  auto nextarc = [&](int v, int w) -> int {
    int nb[4], eg[4]; int deg=0;
    int r=v>>6, c=v&63;
    if (c>0  && (s_mst[r*63+c-1]&1)){ nb[deg]=v-1;  eg[deg]=r*63+c-1; ++deg; }
    if (c<63 && (s_mst[r*63+c]&1))  { nb[deg]=v+1;  eg[deg]=r*63+c;   ++deg; }
    if (r>0  && (s_mst[NEH+v-64]&1)){ nb[deg]=v-64; eg[deg]=NEH+v-64; ++deg; }
    if (r<63 && (s_mst[NEH+v]&1))  { nb[deg]=v+64; eg[deg]=NEH+v;    ++deg; }
    int j=0;
    for (int k2=0;k2<deg;++k2) if (nb[k2]==w) j=k2;
    int jn=j+1;
    if (jn==deg){ if (v==0) return SENT; jn=0; }
    int e2=eg[jn], w2=nb[jn];
    return 2*(int)s_t[e2] + ((v<w2)?0:1);
  };

  // build packed (succ<<16)|dist; non-tree arcs self-loop with dist 0
  __syncthreads();
  for (int i=tid;i<8192;i+=1024) arr[i] = ((u32)i << 16);
  __syncthreads();
  for (int e=tid;e<NE;e+=1024){
    if (s_mst[e]&1){
      int t=s_t[e], u,v; edge_uv(e,u,v);
      arr[2*t]   = ((u32)nextarc(v,u) << 16) | 1u;   // arc u->v (head v)
      arr[2*t+1] = ((u32)nextarc(u,v) << 16) | 1u;   // arc v->u (head u)
    }
  }
  __syncthreads();

  // Wyllie (single pass, packed): dist-to-end in low 16, succ in high 16
  u32 reg8[8];
  #pragma unroll
  for (int k=0;k<8;++k) reg8[k] = arr[tid+(k<<10)];
  for (int rd=0; rd<13; ++rd){
    u32 o8[8];
    #pragma unroll
    for (int k=0;k<8;++k) o8[k] = arr[reg8[k] >> 16];
    __syncthreads();
    #pragma unroll
    for (int k=0;k<8;++k){
      reg8[k] = (o8[k] & 0xFFFF0000u) | ((reg8[k] + o8[k]) & 0xFFFFu);
      arr[tid+(k<<10)] = reg8[k];
    }
    __syncthreads();
  }

  // per-edge: down-arc = earlier in tour (larger dist); positions pos = m - dist
  const int m = 8190;
  u32 pk[8]; int has[8];
  #pragma unroll
  for (int k=0;k<8;++k){
    int e = tid + (k<<10); has[k] = 0;
    if (e < NE && (s_mst[e]&1)){
      int t = s_t[e];
      int d0 = (int)(arr[2*t] & 0xFFFFu), d1 = (int)(arr[2*t+1] & 0xFFFFu);
      int down = (d0 > d1) ? 1 : 0;               // 1: arc (u->v) is the down arc
      int posD = m - (down ? d0 : d1);
      int posU = m - (down ? d1 : d0);
      pk[k] = (u32)posD | ((u32)posU << 13) | ((u32)down << 26);
      has[k] = 1;
    }
  }
  __syncthreads();   // all reads of arr done before scatter overwrites region

  // scatter +/-1 by tour position into short[8192]; positions 0..8189 covered bijectively
  if (tid < 2) pfx[8190 + tid] = 0;
  #pragma unroll
  for (int k=0;k<8;++k){
    if (has[k]){
      pfx[pk[k] & 0x1FFFu] = 1;
      pfx[(pk[k] >> 13) & 0x1FFFu] = -1;
    }
  }
  __syncthreads();
  // hierarchical inclusive scan over short[8192] (int accumulation, exact)
  {
    int v[8];
    #pragma unroll
    for (int j=0;j<8;++j) v[j] = (int)pfx[tid*8+j];
    #pragma unroll
    for (int j=1;j<8;++j) v[j] += v[j-1];
    int mytot = v[7];
    int inc = mytot;
    #pragma unroll
    for (int o=1;o<64;o<<=1){ int n = __shfl_up(inc,o); if (lane>=o) inc += n; }
    if (lane==63) s_wt[wid] = (u32)inc;
    __syncthreads();
    if (tid<16){
      int x = (int)s_wt[tid];
      #pragma unroll
      for (int o=1;o<16;o<<=1){ int n = __shfl_up(x,o); if (tid>=o) x += n; }
      s_wt[tid] = (u32)x;
    }
    __syncthreads();
    int tb = ((wid>0)? (int)s_wt[wid-1] : 0) + (inc - mytot);
    #pragma unroll
    for (int j=0;j<8;++j) pfx[tid*8+j] = (short)(v[j] + tb);
  }
  __syncthreads();

  // depth[child] = inclusive prefix at down-arc position; parent from orientation
  int chld[8], prnt[8], dpv[8];
  #pragma unroll
  for (int k=0;k<8;++k){
    int e = tid + (k<<10); chld[k] = -1;
    if (has[k]){
      int u,v; edge_uv(e,u,v);
      int down = (pk[k] >> 26) & 1;
      chld[k] = down ? v : u;
      prnt[k] = down ? u : v;
      dpv[k]  = (int)pfx[pk[k] & 0x1FFFu];
    }
  }
  __syncthreads();   // all reads of s_t/pfx done before overwriting s_comp region
  #pragma unroll
  for (int k=0;k<8;++k) if (chld[k]>=0){ s_dep[chld[k]]=(u16)dpv[k]; s_parr[chld[k]]=(u16)prnt[k]; }
  if (tid==0){ s_dep[0]=0; s_parr[0]=0; }
  __syncthreads();

  // ---- level histogram + min-node + scan + level-ordered meta scatter ----
  for (int i=tid;i<4096;i+=1024) cnt32[i] = 0;
  if (tid==0) s_maxd = 0;
  __syncthreads();
  #pragma unroll
  for (int t=0;t<4;++t){
    int i = (tid<<2) + t;
    u32 dd = s_dep[i];
    atomicAdd(&cnt32[dd], 1u);
    atomicMax((u32*)&s_maxd, dd);
    atomicMin(&lmin_g[b*4096 + (int)dd], i);
  }
  __syncthreads();
  int md = (int)s_maxd;
  // hierarchical inclusive scan over cnt32[4096]
  {
    u32 v[4];
    #pragma unroll
    for (int j=0;j<4;++j) v[j] = cnt32[tid*4+j];
    #pragma unroll
    for (int j=1;j<4;++j) v[j] += v[j-1];
    u32 mytot = v[3];
    u32 inc = mytot;
    #pragma unroll
    for (int o=1;o<64;o<<=1){ u32 n = __shfl_up(inc,o); if (lane>=o) inc += n; }
    if (lane==63) s_wt[wid] = inc;
    __syncthreads();
    if (tid<16){
      u32 x = s_wt[tid];
      #pragma unroll
      for (int o=1;o<16;o<<=1){ u32 n = __shfl_up(x,o); if (tid>=o) x += n; }
      s_wt[tid] = x;
    }
    __syncthreads();
    u32 tb = ((wid>0)? s_wt[wid-1] : 0u) + (inc - mytot);
    #pragma unroll
    for (int j=0;j<4;++j) cnt32[tid*4+j] = v[j] + tb;
  }
  __syncthreads();
  for (int i=tid; i<4097; i+=1024){
    int ls = (i==0) ? 0 : (int)cnt32[i-1];
    level_start_g[b*4104 + i] = ls;
  }
  u32 ex4[4];
  #pragma unroll
  for (int t=0;t<4;++t){ int i = tid + (t<<10); ex4[t] = (i==0) ? 0u : cnt32[i-1]; }
  __syncthreads();
  #pragma unroll
  for (int t=0;t<4;++t){ int i = tid + (t<<10); cnt32[i] = ex4[t]; }
  __syncthreads();
  #pragma unroll
  for (int t=0;t<4;++t){
    int i = (tid<<2) + t;
    u32 pos = atomicAdd(&cnt32[s_dep[i]], 1u);
    meta_g[b*4096 + (int)pos] = i | ((int)s_parr[i] << 16);   // v | parent<<16, level-ordered
  }
  if (tid==0) maxd_g[b] = md;
}

// ---------------- K5b: mark pad-keeper nodes: bit 12 of meta on the lmin node of padded levels ----------------
__global__ __launch_bounds__(256) void k5b_mark(const int* __restrict__ lstart, const int* __restrict__ lmin_g,
                                                int* __restrict__ meta_g){
  int d = blockIdx.x*256 + threadIdx.x;
  if (d == 0 || d >= 4096) return;
  int cnts[NB]; int mx = 0;
  #pragma unroll
  for (int b=0;b<NB;++b){
    int c = lstart[b*4104 + d + 1] - lstart[b*4104 + d];
    cnts[b] = c; if (c > mx) mx = c;
  }
  #pragma unroll
  for (int b=0;b<NB;++b){
    if (cnts[b] > 0 && cnts[b] < mx){
      int keeper = lmin_g[b*4096 + d];
      int st = lstart[b*4104 + d];
      for (int p2=st; p2<st+cnts[b]; ++p2){
        int idx = b*4096 + p2;
        if ((meta_g[idx] & 4095) == keeper){ meta_g[idx] |= 0x1000; break; }
      }
    }
  }
}

// ---------------- K5c: permute ew into LEVEL order per (b,ch), in place via LDS staging ----------------
__global__ __launch_bounds__(256) void k5c_permute(const int* __restrict__ meta_g, float* __restrict__ ew_cm){
  __shared__ float se[4096];
  const int bid = blockIdx.x;
  const int b = bid / ND, ch = bid - b*ND;
  float* ewc = ew_cm + ((size_t)(b*ND + ch))*NL;
  const int* mg = meta_g + b*4096;
  for (int i=threadIdx.x; i<1024; i+=256) ((float4*)se)[i] = ((const float4*)ewc)[i];
  __syncthreads();
  for (int p=threadIdx.x; p<NL; p+=256) ewc[p] = se[mg[p] & 4095];
}

// ---------------- K6: LDS-resident tree scan, one wave per (batch, channel); CM output ----------------
// R10-exact (session best, 151.5us): R1 structure, no per-level fences (single-wave DS ops complete
// in order), 8-slot rolling register pipeline prefetching (meta, ew) 8-16 levels ahead, single chunk
// (R11's 2-chunk prefetch overran the VMEM issue queue: +35us — reverted).
__global__ __launch_bounds__(64) void k6_scan(const float* __restrict__ ewlo_cm, const float* __restrict__ up_cm,
                                              float* __restrict__ aggr_cm, const int* __restrict__ meta_g,
                                              const int* __restrict__ lstart, const int* __restrict__ maxd_g){
  __shared__ float s_ua[4096];      // BX -> up -> aggr (in-place), 16 KB
  __shared__ u64   s_ls64[1026];    // level starts as u16[4104], 8.2 KB (u64-aligned for packed writes)
  u16* s_ls = (u16*)s_ls64;
  const int bid = blockIdx.x;
  const int b = bid / ND, ch = bid - b*ND;
  const int lane = threadIdx.x;
  const int md = maxd_g[b];
  const float* el = ewlo_cm + ((size_t)(b*ND + ch))*NL;   // ew in LEVEL order
  const float* upc = up_cm + ((size_t)(b*ND + ch))*NL;
  const int* mg = meta_g + b*4096;

  // stage level starts (vectorized: int4 global read -> 4x u16 packed into one b64 LDS write)
  {
    const int4* ls4 = (const int4*)(lstart + b*4104);
    int n4 = (md + 2 + 3) >> 2;              // entries 0..md+1 needed
    for (int i=lane; i<n4; i+=64){
      int4 t = ls4[i];
      u64 pkv = (u64)(u16)t.x | ((u64)(u16)t.y<<16) | ((u64)(u16)t.z<<32) | ((u64)(u16)t.w<<48);
      s_ls64[i] = pkv;
    }
  }
  // stage BX
  for (int i=lane; i<1024; i+=64) ((float4*)s_ua)[i] = ((const float4*)upc)[i];

  // 8-slot rolling pipeline state (static indices only; macros keep everything in registers)
  #define K6_DECL(k) int stS##k=0, cS##k=0, mS##k=0; float wS##k=0.f;
  K6_DECL(0) K6_DECL(1) K6_DECL(2) K6_DECL(3) K6_DECL(4) K6_DECL(5) K6_DECL(6) K6_DECL(7)

  // ---- up-sweep: levels md..1 ----
  #define K6_LOADU(k, dexpr) { int dd_=(dexpr); cS##k=0; if (dd_>=1){ \
      stS##k=(int)s_ls[dd_]; cS##k=(int)s_ls[dd_+1]-stS##k; \
      if (lane<cS##k){ mS##k=mg[stS##k+lane]; wS##k=el[stS##k+lane]; } } }
  #define K6_PROCU(k) { if (lane<cS##k){ \
      int v_=mS##k&4095, p_=(mS##k>>16)&4095; \
      atomicAdd(&s_ua[p_], wS##k*s_ua[v_]); } \
    for (int i_=lane+64;i_<cS##k;i_+=64){ \
      int m_=mg[stS##k+i_]; float ww_=el[stS##k+i_]; \
      int v_=m_&4095, p_=(m_>>16)&4095; \
      atomicAdd(&s_ua[p_], ww_*s_ua[v_]); } }

  K6_LOADU(0, md)   K6_LOADU(1, md-1) K6_LOADU(2, md-2) K6_LOADU(3, md-3)
  K6_LOADU(4, md-4) K6_LOADU(5, md-5) K6_LOADU(6, md-6) K6_LOADU(7, md-7)
  for (int base = md; base >= 1; base -= 8){
    K6_PROCU(0) K6_PROCU(1) K6_PROCU(2) K6_PROCU(3)
    K6_PROCU(4) K6_PROCU(5) K6_PROCU(6) K6_PROCU(7)
    K6_LOADU(0, base-8)  K6_LOADU(1, base-9)  K6_LOADU(2, base-10) K6_LOADU(3, base-11)
    K6_LOADU(4, base-12) K6_LOADU(5, base-13) K6_LOADU(6, base-14) K6_LOADU(7, base-15)
  }

  // ---- down-sweep: levels 1..md, same pipelining; pad keeper via bit 12 of meta ----
  #define K6_LOADD(k, dexpr) { int dd_=(dexpr); cS##k=0; if (dd_<=md){ \
      stS##k=(int)s_ls[dd_]; cS##k=(int)s_ls[dd_+1]-stS##k; \
      if (lane<cS##k){ mS##k=mg[stS##k+lane]; wS##k=el[stS##k+lane]; } } }
  #define K6_PROCD(k) { if (lane<cS##k){ \
      int m_=mS##k; float ww_=wS##k; \
      int v_=m_&4095, p_=(m_>>16)&4095; \
      float uv_=s_ua[v_]; \
      float r_=uv_+ww_*(s_ua[p_]-ww_*uv_); \
      if (m_&0x1000) r_=uv_; \
      s_ua[v_]=r_; } \
    for (int i_=lane+64;i_<cS##k;i_+=64){ \
      int m_=mg[stS##k+i_]; float ww_=el[stS##k+i_]; \
      int v_=m_&4095, p_=(m_>>16)&4095; \
      float uv_=s_ua[v_]; \
      float r_=uv_+ww_*(s_ua[p_]-ww_*uv_); \
      if (m_&0x1000) r_=uv_; \
      s_ua[v_]=r_; } }

  K6_LOADD(0, 1) K6_LOADD(1, 2) K6_LOADD(2, 3) K6_LOADD(3, 4)
  K6_LOADD(4, 5) K6_LOADD(5, 6) K6_LOADD(6, 7) K6_LOADD(7, 8)
  for (int base = 1; base <= md; base += 8){
    K6_PROCD(0) K6_PROCD(1) K6_PROCD(2) K6_PROCD(3)
    K6_PROCD(4) K6_PROCD(5) K6_PROCD(6) K6_PROCD(7)
    K6_LOADD(0, base+8)  K6_LOADD(1, base+9)  K6_LOADD(2, base+10) K6_LOADD(3, base+11)
    K6_LOADD(4, base+12) K6_LOADD(5, base+13) K6_LOADD(6, base+14) K6_LOADD(7, base+15)
  }

  #undef K6_DECL
  #undef K6_LOADU
  #undef K6_PROCU
  #undef K6_LOADD
  #undef K6_PROCD

  // write back CHANNEL-MAJOR: contiguous 16 KB per block, float4, fully coalesced full lines
  float* outc = aggr_cm + ((size_t)(b*ND + ch))*NL;
  for (int i=lane; i<1024; i+=64) ((float4*)outc)[i] = ((const float4*)s_ua)[i];
}

// ---------------- K7+K8 fused: LN(h)*Cs + Ds*xs -> LN -> *z -> GEMM @ out_proj_w.T ----------------
__global__ __launch_bounds__(256) void k7k8(const float* __restrict__ aggr_cm, const float* __restrict__ xs,
                                            const float* __restrict__ z, const float* __restrict__ Cs,
                                            const float* __restrict__ Dsw, const float* __restrict__ hg,
                                            const float* __restrict__ hb, const float* __restrict__ og,
                                            const float* __restrict__ ob, const float* __restrict__ w2,
                                            float* __restrict__ out){
  __shared__ float tile[192*33];    // phase1: h [d][lcol]; phase2: y [k][row] (same layout)
  __shared__ float sw[96*97];       // w2 chunk transposed [k][o0..95]
  const int b  = blockIdx.x >> 7;          // 8 batches
  const int l0 = (blockIdx.x & 127) * 32;  // 128 tiles of 32 rows
  const int tid = threadIdx.x;

  for (int i=tid; i<192*32; i+=256){
    int ch = i >> 5, lcol = i & 31;
    tile[ch*33 + lcol] = aggr_cm[((size_t)(b*ND + ch))*NL + l0 + lcol];
  }
  __syncthreads();

  const int wv = tid >> 6, lane = tid & 63;
  float yv[8][3];
  for (int s=0; s<8; ++s){
    int lcol = wv*8 + s;
    int gid = b*NL + l0 + lcol;
    float h[3], x3[3], z3[3];
    #pragma unroll
    for (int j=0;j<3;++j){
      int d = lane + 64*j;
      h[j]  = tile[d*33 + lcol];
      x3[j] = xs[(size_t)gid*ND + d];
      z3[j] = z[(size_t)gid*ND + d];
    }
    float mu  = wred_f(h[0]+h[1]+h[2]) / 192.f;
    float vs = 0.f;
    #pragma unroll
    for (int j=0;j<3;++j){ float t = h[j]-mu; vs += t*t; }
    float inv = 1.f / sqrtf(wred_f(vs)/192.f + 1e-5f);
    float Cv = Cs[gid];
    float y[3];
    #pragma unroll
    for (int j=0;j<3;++j){
      int d = lane + 64*j;
      float hn = (h[j]-mu)*inv*hg[d] + hb[d];
      y[j] = hn*Cv + Dsw[d]*x3[j];
    }
    float mu2 = wred_f(y[0]+y[1]+y[2]) / 192.f;
    float vs2 = 0.f;
    #pragma unroll
    for (int j=0;j<3;++j){ float t = y[j]-mu2; vs2 += t*t; }
    float inv2 = 1.f / sqrtf(wred_f(vs2)/192.f + 1e-5f);
    #pragma unroll
    for (int j=0;j<3;++j){
      int d = lane + 64*j;
      float o = (y[j]-mu2)*inv2*og[d] + ob[d];
      yv[s][j] = o*z3[j];
    }
  }
  __syncthreads();             // all h reads done
  #pragma unroll
  for (int s=0; s<8; ++s){
    int lcol = wv*8 + s;
    #pragma unroll
    for (int j=0;j<3;++j){
      int d = lane + 64*j;
      tile[d*33 + lcol] = yv[s][j];   // y into same slot/layout
    }
  }

  // ---- GEMM phase: out[32 x 96] = y[32 x 192] @ w2^T, K split 2x96 (bit-identical to old k8) ----
  const int rq = tid >> 5;          // 0..7 -> rows rq*4..rq*4+3
  const int cq = tid & 31;          // 0..31 -> cols cq*3..cq*3+2
  float acc[4][3];
  #pragma unroll
  for (int a=0;a<4;++a)
    #pragma unroll
    for (int bcl=0;bcl<3;++bcl) acc[a][bcl] = 0.f;

  for (int kc=0; kc<2; ++kc){
    __syncthreads();
    for (int i=tid; i<96*96; i+=256){
      int o = i/96, k = i - o*96;
      sw[k*97 + o] = w2[(size_t)o*ND + kc*96 + k];
    }
    __syncthreads();
    #pragma unroll 4
    for (int k=0;k<96;++k){
      float4 ya = *(const float4*)&tile[(kc*96 + k)*33 + rq*4];
      float w0 = sw[k*97 + cq*3 + 0];
      float w1 = sw[k*97 + cq*3 + 1];
      float wvv = sw[k*97 + cq*3 + 2];
      acc[0][0] += ya.x*w0; acc[0][1] += ya.x*w1; acc[0][2] += ya.x*wvv;
      acc[1][0] += ya.y*w0; acc[1][1] += ya.y*w1; acc[1][2] += ya.y*wvv;
      acc[2][0] += ya.z*w0; acc[2][1] += ya.z*w1; acc[2][2] += ya.z*wvv;
      acc[3][0] += ya.w*w0; acc[3][1] += ya.w*w1; acc[3][2] += ya.w*wvv;
    }
  }

  #pragma unroll
  for (int a=0;a<4;++a){
    size_t row = (size_t)b*NL + l0 + rq*4 + a;
    #pragma unroll
    for (int bcl=0;bcl<3;++bcl){
      out[row*NDM + cq*3 + bcl] = acc[a][bcl];
    }
  }
}

extern "C" void kernel_launch(void* const* d_in, const int* in_sizes, int n_in,
                              void* d_out, int out_size, void* d_ws, size_t ws_size,
                              hipStream_t stream){
  const float* x    = (const float*)d_in[0];
  const float* inw  = (const float*)d_in[1];
  const float* cw   = (const float*)d_in[2];
  const float* cb   = (const float*)d_in[3];
  const float* xpw  = (const float*)d_in[4];
  const float* dtw  = (const float*)d_in[5];
  const float* dtb  = (const float*)d_in[6];
  const float* alog = (const float*)d_in[7];
  const float* Dsw  = (const float*)d_in[8];
  const float* hg   = (const float*)d_in[9];
  const float* hb   = (const float*)d_in[10];
  const float* og   = (const float*)d_in[11];
  const float* ob   = (const float*)d_in[12];
  const float* w2   = (const float*)d_in[13];
  float* out = (float*)d_out;

  const size_t S = (size_t)NB*NL*ND;   // 6,291,456 elems per f32 buffer
  float* bufA  = (float*)d_ws;         // xc_pre
  float* bufZ  = bufA + S;             // silu(z)
  float* bufX  = bufZ + S;             // xs (post-conv silu)
  float* ew_cm = bufX + S;             // deltaA, channel-major; k5c permutes to LEVEL order in place
  float* up_cm = ew_cm + S;            // BX, channel-major [b][d][l]
  float* bufG  = up_cm + S;            // aggr, channel-major [b][d][l]
  char* q = (char*)(bufG + S);
  double* norms = (double*)q;                q += (size_t)NB*NL*sizeof(double);
  u64* keys     = (u64*)q;                   q += (size_t)NB*NE*sizeof(u64);
  float* Cs     = (float*)q;                 q += (size_t)NB*NL*sizeof(float);
  int* lstart   = (int*)q;                   q += (size_t)NB*4104*sizeof(int);
  int* maxd     = (int*)q;                   q += 64*sizeof(int);
  int* lmin     = (int*)q;                   q += (size_t)NB*NL*sizeof(int);
  int* meta     = (int*)q;                   q += (size_t)NB*NL*sizeof(int);

  k1_inproj<<<dim3(NB*NL/32*4), dim3(256), 0, stream>>>(x, inw, bufA, bufZ);
  k2_conv  <<<dim3((NB*NL*ND)/256), dim3(256), 0, stream>>>(bufA, cw, cb, bufX);
  k3_ssm   <<<dim3(NB*NL/16), dim3(1024), 0, stream>>>(bufX, xpw, dtw, dtb, alog, ew_cm, up_cm, Cs, norms);
  k4_keys  <<<dim3(NB*NE/4), dim3(256), 0, stream>>>(bufX, norms, keys);
  k5_tree  <<<dim3(NB), dim3(1024), 0, stream>>>(keys, meta, lstart, maxd, lmin);
  k5b_mark <<<dim3(16), dim3(256), 0, stream>>>(lstart, lmin, meta);
  k5c_permute<<<dim3(NB*ND), dim3(256), 0, stream>>>(meta, ew_cm);
  k6_scan  <<<dim3(NB*ND), dim3(64), 0, stream>>>(ew_cm, up_cm, bufG, meta, lstart, maxd);
  k7k8     <<<dim3(NB*128), dim3(256), 0, stream>>>(bufG, bufX, bufZ, Cs, Dsw, hg, hb, og, ob, w2, out);
}